// Round 4
// baseline (305.230 us; speedup 1.0000x reference)
//
#include <hip/hip_runtime.h>
#include <hip/hip_cooperative_groups.h>
#include <math.h>

namespace cg = cooperative_groups;

#define NT   196
#define EMB  256
#define NH   8
#define DH   32
#define HID  1024
#define EPSV 1e-5f

struct Params {
    const float *vis, *ir;
    const float *l1vw, *l1vb, *l1iw, *l1ib;
    const float *l2vw, *l2vb, *l2iw, *l2ib;
    const float *Wqv, *bqv, *Wqi, *bqi;
    const float *Wpv, *bpv, *Wpi, *bpi;
    const float *W1v, *b1v, *W2v, *b2v;
    const float *W1i, *b1i, *W2i, *b2i;
    float *Q, *K, *V, *AO, *LV, *HH;
    float *out;
};

// 4x4-register-blocked 64-iter K-panel: 1 float4 W load + 1 broadcast b128 X
// read + 16 fma per iter. Threads: cq = t&63 (col quad), ks = t>>6 (K split).
#define GEMM_PANEL(Wptr, ldw, xsT, pp, cq, ks, KITER)                          \
    {                                                                          \
        const float* Wb = (Wptr);                                              \
        float4 a0 = {0,0,0,0}, a1 = a0, a2 = a0, a3 = a0;                      \
        _Pragma("unroll 8")                                                    \
        for (int kk = (ks) * (KITER); kk < (ks) * (KITER) + (KITER); kk++) {   \
            float4 w4 = *(const float4*)&Wb[kk * (ldw)];                       \
            float4 xr = *(const float4*)&(xsT)[kk * 4];                        \
            a0.x = fmaf(xr.x, w4.x, a0.x); a0.y = fmaf(xr.x, w4.y, a0.y);      \
            a0.z = fmaf(xr.x, w4.z, a0.z); a0.w = fmaf(xr.x, w4.w, a0.w);      \
            a1.x = fmaf(xr.y, w4.x, a1.x); a1.y = fmaf(xr.y, w4.y, a1.y);      \
            a1.z = fmaf(xr.y, w4.z, a1.z); a1.w = fmaf(xr.y, w4.w, a1.w);      \
            a2.x = fmaf(xr.z, w4.x, a2.x); a2.y = fmaf(xr.z, w4.y, a2.y);      \
            a2.z = fmaf(xr.z, w4.z, a2.z); a2.w = fmaf(xr.z, w4.w, a2.w);      \
            a3.x = fmaf(xr.w, w4.x, a3.x); a3.y = fmaf(xr.w, w4.y, a3.y);      \
            a3.z = fmaf(xr.w, w4.z, a3.z); a3.w = fmaf(xr.w, w4.w, a3.w);      \
        }                                                                      \
        *(float4*)&(pp)[((ks) * 4 + 0) * 256 + (cq) * 4] = a0;                 \
        *(float4*)&(pp)[((ks) * 4 + 1) * 256 + (cq) * 4] = a1;                 \
        *(float4*)&(pp)[((ks) * 4 + 2) * 256 + (cq) * 4] = a2;                 \
        *(float4*)&(pp)[((ks) * 4 + 3) * 256 + (cq) * 4] = a3;                 \
    }

__global__ void fused_crossvit(Params p)
{
    cg::grid_group grid = cg::this_grid();
    // LDS union across stages; max = attention stage: 2*196*33 + 4*196 floats.
    __shared__ float smem[13720];
    const int t = threadIdx.x;

    // ================= Stage 1: QKV (raw x @ Wqkv + bias, de-interleave) ====
    // 294 units = 2 streams x 49 token-tiles x 3 col-groups
    {
        float* xsT = smem;          // [256][4]
        float* pp  = smem + 1024;   // [4][4][256]
        for (int u = blockIdx.x; u < 294; u += gridDim.x) {
            const int s = u / 147;
            const int rem = u % 147;
            const int n0 = (rem / 3) * 4;
            const int cg_ = rem % 3;
            const float* x    = (s == 0) ? p.vis : p.ir;
            const float* W    = (s == 0) ? p.Wqv : p.Wqi;
            const float* bias = (s == 0) ? p.bqv : p.bqi;
            {
                int r = t >> 6, c4 = (t & 63) * 4;
                float4 xv = *(const float4*)&x[(n0 + r) * EMB + c4];
                xsT[(c4 + 0) * 4 + r] = xv.x;
                xsT[(c4 + 1) * 4 + r] = xv.y;
                xsT[(c4 + 2) * 4 + r] = xv.z;
                xsT[(c4 + 3) * 4 + r] = xv.w;
            }
            __syncthreads();
            const int cq = t & 63, ks = t >> 6;
            GEMM_PANEL(W + cg_ * 256 + cq * 4, 768, xsT, pp, cq, ks, 64);
            __syncthreads();
            const int col = cg_ * 256 + t;
            const int h = col / 96, rr = col % 96, d = rr / 3, q = rr % 3;
            float* dst = (q == 0) ? p.Q : (q == 1 ? p.K : p.V);
            const float bval = bias[col];
            #pragma unroll
            for (int r = 0; r < 4; r++) {
                float v = pp[(0 * 4 + r) * 256 + t] + pp[(1 * 4 + r) * 256 + t]
                        + pp[(2 * 4 + r) * 256 + t] + pp[(3 * 4 + r) * 256 + t] + bval;
                dst[((s * NH + h) * NT + n0 + r) * DH + d] = v;
            }
            __syncthreads();
        }
    }
    grid.sync();

    // ================= Stage 2: cross-attention =============================
    // 224 units = 2 streams x 8 heads x 14 row-tiles
    {
        float* kl = smem;               // [196][33]
        float* vl = smem + 6468;        // [196][33]
        float* pb = smem + 12936;       // [4][196]
        const int wv = t >> 6, lane = t & 63;
        for (int u = blockIdx.x; u < 224; u += gridDim.x) {
            const int s  = u / 112;
            const int rm = u % 112;
            const int h  = rm / 14;
            const int rt = rm % 14;
            const float4* Ks4 = (const float4*)(p.K + ((1 - s) * NH + h) * NT * DH);
            const float4* Vs4 = (const float4*)(p.V + ((1 - s) * NH + h) * NT * DH);
            for (int idx = t; idx < NT * 8; idx += 256) {
                int j = idx >> 3, d4 = (idx & 7) * 4;
                float4 kv = Ks4[idx];
                kl[j * 33 + d4 + 0] = kv.x; kl[j * 33 + d4 + 1] = kv.y;
                kl[j * 33 + d4 + 2] = kv.z; kl[j * 33 + d4 + 3] = kv.w;
                float4 vv = Vs4[idx];
                vl[j * 33 + d4 + 0] = vv.x; vl[j * 33 + d4 + 1] = vv.y;
                vl[j * 33 + d4 + 2] = vv.z; vl[j * 33 + d4 + 3] = vv.w;
            }
            __syncthreads();
            const float* Qs = p.Q + ((s * NH + h) * NT) * DH;
            const bool v3 = (lane + 192) < NT;
            const int  j3 = v3 ? (lane + 192) : 0;
            for (int it = 0; it < 4; it++) {
                int lr = it * 4 + wv;
                bool act = lr < 14;
                int i = rt * 14 + lr;
                float inv_sum = 0.0f;
                if (act) {
                    float qreg[DH];
                    #pragma unroll
                    for (int d = 0; d < DH; d++) qreg[d] = Qs[i * DH + d];
                    float s0 = 0.f, s1 = 0.f, s2 = 0.f, s3 = 0.f;
                    #pragma unroll
                    for (int d = 0; d < DH; d++) {
                        float qd = qreg[d];
                        s0 = fmaf(qd, kl[(lane      ) * 33 + d], s0);
                        s1 = fmaf(qd, kl[(lane +  64) * 33 + d], s1);
                        s2 = fmaf(qd, kl[(lane + 128) * 33 + d], s2);
                        s3 = fmaf(qd, kl[ j3          * 33 + d], s3);
                    }
                    const float sc = 1.0f / 16.0f;
                    s0 *= sc; s1 *= sc; s2 *= sc; s3 *= sc;
                    float m = fmaxf(fmaxf(s0, s1), v3 ? fmaxf(s2, s3) : s2);
                    #pragma unroll
                    for (int mk = 32; mk >= 1; mk >>= 1) m = fmaxf(m, __shfl_xor(m, mk));
                    float p0 = expf(s0 - m), p1 = expf(s1 - m), p2 = expf(s2 - m);
                    float p3 = v3 ? expf(s3 - m) : 0.0f;
                    float ls = p0 + p1 + p2 + p3;
                    #pragma unroll
                    for (int mk = 32; mk >= 1; mk >>= 1) ls += __shfl_xor(ls, mk);
                    inv_sum = 1.0f / ls;
                    pb[wv * NT + lane]       = p0;
                    pb[wv * NT + lane +  64] = p1;
                    pb[wv * NT + lane + 128] = p2;
                    if (v3) pb[wv * NT + lane + 192] = p3;
                }
                __syncthreads();
                if (act) {
                    int d = lane & 31, half = lane >> 5;
                    float o = 0.0f;
                    int jb = half * 98;
                    for (int jj = 0; jj < 98; jj++) {
                        int j = jb + jj;
                        o = fmaf(pb[wv * NT + j], vl[j * 33 + d], o);
                    }
                    o += __shfl_xor(o, 32);
                    if (lane < 32) p.AO[(s * NT + i) * EMB + h * DH + d] = o * inv_sum;
                }
                __syncthreads();
            }
        }
    }
    grid.sync();

    // ================= Stage 3: proj + LN1(x) residual + LN2 ================
    // 98 units = 2 streams x 49 token-tiles
    {
        float* aoT  = smem;           // [256][4]
        float* pp   = smem + 1024;    // [4][4][256]
        float* nvb  = smem + 5120;    // [4][256]
        float* rbuf = smem + 6144;    // [4][256]
        const int r = t >> 6, lane = t & 63, c4 = lane * 4;
        for (int u = blockIdx.x; u < 98; u += gridDim.x) {
            const int s = u / 49;
            const int n0 = (u % 49) * 4;
            const float* x   = (s == 0) ? p.vis  : p.ir;
            const float* W   = (s == 0) ? p.Wpv  : p.Wpi;
            const float* bp  = (s == 0) ? p.bpv  : p.bpi;
            const float* l1w = (s == 0) ? p.l1vw : p.l1iw;
            const float* l1b = (s == 0) ? p.l1vb : p.l1ib;
            const float* l2w = (s == 0) ? p.l2vw : p.l2iw;
            const float* l2b = (s == 0) ? p.l2vb : p.l2ib;
            {
                float4 xv = *(const float4*)&x[(n0 + r) * EMB + c4];
                float sum = xv.x + xv.y + xv.z + xv.w;
                float sq  = xv.x*xv.x + xv.y*xv.y + xv.z*xv.z + xv.w*xv.w;
                #pragma unroll
                for (int mk = 32; mk >= 1; mk >>= 1) {
                    sum += __shfl_xor(sum, mk);
                    sq  += __shfl_xor(sq,  mk);
                }
                float mean = sum * (1.0f / EMB);
                float inv  = rsqrtf(sq * (1.0f / EMB) - mean * mean + EPSV);
                float4 wv4 = *(const float4*)&l1w[c4];
                float4 bv4 = *(const float4*)&l1b[c4];
                nvb[r * 256 + c4 + 0] = (xv.x - mean) * inv * wv4.x + bv4.x;
                nvb[r * 256 + c4 + 1] = (xv.y - mean) * inv * wv4.y + bv4.y;
                nvb[r * 256 + c4 + 2] = (xv.z - mean) * inv * wv4.z + bv4.z;
                nvb[r * 256 + c4 + 3] = (xv.w - mean) * inv * wv4.w + bv4.w;
                float4 av = *(const float4*)&p.AO[(s * NT + n0 + r) * EMB + c4];
                aoT[(c4 + 0) * 4 + r] = av.x;
                aoT[(c4 + 1) * 4 + r] = av.y;
                aoT[(c4 + 2) * 4 + r] = av.z;
                aoT[(c4 + 3) * 4 + r] = av.w;
            }
            __syncthreads();
            const int cq = t & 63, ks = t >> 6;
            GEMM_PANEL(W + cq * 4, EMB, aoT, pp, cq, ks, 64);
            __syncthreads();
            {
                const float bval = bp[t];
                #pragma unroll
                for (int r2 = 0; r2 < 4; r2++) {
                    float v = pp[(0 * 4 + r2) * 256 + t] + pp[(1 * 4 + r2) * 256 + t]
                            + pp[(2 * 4 + r2) * 256 + t] + pp[(3 * 4 + r2) * 256 + t]
                            + bval + nvb[r2 * 256 + t];
                    rbuf[r2 * 256 + t] = v;
                }
            }
            __syncthreads();
            {
                float4 rv = *(const float4*)&rbuf[r * 256 + c4];
                float sum = rv.x + rv.y + rv.z + rv.w;
                float sq  = rv.x*rv.x + rv.y*rv.y + rv.z*rv.z + rv.w*rv.w;
                #pragma unroll
                for (int mk = 32; mk >= 1; mk >>= 1) {
                    sum += __shfl_xor(sum, mk);
                    sq  += __shfl_xor(sq,  mk);
                }
                float mean = sum * (1.0f / EMB);
                float inv  = rsqrtf(sq * (1.0f / EMB) - mean * mean + EPSV);
                float4 wv4 = *(const float4*)&l2w[c4];
                float4 bv4 = *(const float4*)&l2b[c4];
                float4 o;
                o.x = (rv.x - mean) * inv * wv4.x + bv4.x;
                o.y = (rv.y - mean) * inv * wv4.y + bv4.y;
                o.z = (rv.z - mean) * inv * wv4.z + bv4.z;
                o.w = (rv.w - mean) * inv * wv4.w + bv4.w;
                *(float4*)&p.LV[(s * NT + n0 + r) * EMB + c4] = o;
            }
            __syncthreads();
        }
    }
    grid.sync();

    // ================= Stage 4: FFN1 + exact GELU ===========================
    // 392 units = 2 streams x 49 token-tiles x 4 col-groups
    {
        float* xsT = smem;
        float* pp  = smem + 1024;
        for (int u = blockIdx.x; u < 392; u += gridDim.x) {
            const int s = u / 196;
            const int rem = u % 196;
            const int n0 = (rem / 4) * 4;
            const int cg_ = rem % 4;
            const float* W  = (s == 0) ? p.W1v : p.W1i;
            const float* bb = (s == 0) ? p.b1v : p.b1i;
            {
                int r = t >> 6, c4 = (t & 63) * 4;
                float4 xv = *(const float4*)&p.LV[(s * NT + n0 + r) * EMB + c4];
                xsT[(c4 + 0) * 4 + r] = xv.x;
                xsT[(c4 + 1) * 4 + r] = xv.y;
                xsT[(c4 + 2) * 4 + r] = xv.z;
                xsT[(c4 + 3) * 4 + r] = xv.w;
            }
            __syncthreads();
            const int cq = t & 63, ks = t >> 6;
            GEMM_PANEL(W + cg_ * 256 + cq * 4, HID, xsT, pp, cq, ks, 64);
            __syncthreads();
            const int col = cg_ * 256 + t;
            const float bval = bb[col];
            #pragma unroll
            for (int r = 0; r < 4; r++) {
                float v = pp[(0 * 4 + r) * 256 + t] + pp[(1 * 4 + r) * 256 + t]
                        + pp[(2 * 4 + r) * 256 + t] + pp[(3 * 4 + r) * 256 + t] + bval;
                float g = 0.5f * v * (1.0f + erff(v * 0.7071067811865475f));
                p.HH[(s * NT + n0 + r) * HID + col] = g;
            }
            __syncthreads();
        }
    }
    grid.sync();

    // ================= Stage 5: FFN2 + residual + patch recon ===============
    // 98 units = 2 streams x 49 token-tiles; K=1024 split 4 ways
    {
        float* hhT = smem;            // [1024][4]
        float* pp  = smem + 4096;     // [4][4][256]
        for (int u = blockIdx.x; u < 98; u += gridDim.x) {
            const int s = u / 49;
            const int n0 = (u % 49) * 4;
            const float* W  = (s == 0) ? p.W2v : p.W2i;
            const float* bb = (s == 0) ? p.b2v : p.b2i;
            {
                int r = t >> 6, lane = t & 63;
                #pragma unroll
                for (int rd = 0; rd < 4; rd++) {
                    int c4 = rd * 256 + lane * 4;
                    float4 hv = *(const float4*)&p.HH[(s * NT + n0 + r) * HID + c4];
                    hhT[(c4 + 0) * 4 + r] = hv.x;
                    hhT[(c4 + 1) * 4 + r] = hv.y;
                    hhT[(c4 + 2) * 4 + r] = hv.z;
                    hhT[(c4 + 3) * 4 + r] = hv.w;
                }
            }
            __syncthreads();
            const int cq = t & 63, ks = t >> 6;
            GEMM_PANEL(W + cq * 4, EMB, hhT, pp, cq, ks, 256);
            __syncthreads();
            const float bval = bb[t];
            const int p1 = t >> 4, p2 = t & 15;
            const int ch = (s == 0) ? 1 : 0;   // channel 0 = ir, 1 = vis
            #pragma unroll
            for (int r = 0; r < 4; r++) {
                int n = n0 + r;
                float v = pp[(0 * 4 + r) * 256 + t] + pp[(1 * 4 + r) * 256 + t]
                        + pp[(2 * 4 + r) * 256 + t] + pp[(3 * 4 + r) * 256 + t]
                        + bval + p.LV[(s * NT + n) * EMB + t];
                int n1 = n / 14, n2 = n % 14;
                int f = p1 * 3136 + p2 * 196 + n1 * 14 + n2;
                p.out[ch * 50176 + f] = v;
            }
            __syncthreads();
        }
    }
}

extern "C" void kernel_launch(void* const* d_in, const int* in_sizes, int n_in,
                              void* d_out, int out_size, void* d_ws, size_t ws_size,
                              hipStream_t stream)
{
    Params p;
    p.vis  = (const float*)d_in[0];
    p.ir   = (const float*)d_in[1];
    p.l1vw = (const float*)d_in[2];
    p.l1vb = (const float*)d_in[3];
    p.l1iw = (const float*)d_in[4];
    p.l1ib = (const float*)d_in[5];
    p.l2vw = (const float*)d_in[6];
    p.l2vb = (const float*)d_in[7];
    p.l2iw = (const float*)d_in[8];
    p.l2ib = (const float*)d_in[9];
    p.Wqv  = (const float*)d_in[10];
    p.bqv  = (const float*)d_in[11];
    p.Wqi  = (const float*)d_in[12];
    p.bqi  = (const float*)d_in[13];
    p.Wpv  = (const float*)d_in[14];
    p.bpv  = (const float*)d_in[15];
    p.Wpi  = (const float*)d_in[16];
    p.bpi  = (const float*)d_in[17];
    p.W1v  = (const float*)d_in[18];
    p.b1v  = (const float*)d_in[19];
    p.W2v  = (const float*)d_in[20];
    p.b2v  = (const float*)d_in[21];
    p.W1i  = (const float*)d_in[22];
    p.b1i  = (const float*)d_in[23];
    p.W2i  = (const float*)d_in[24];
    p.b2i  = (const float*)d_in[25];

    float* ws = (float*)d_ws;
    p.Q  = ws;               // [2][8][196][32]
    p.K  = ws + 100352;
    p.V  = ws + 200704;
    p.AO = ws + 301056;      // [2][196][256]
    p.LV = ws + 401408;      // [2][196][256]
    p.HH = ws + 501760;      // [2][196][1024]
    p.out = (float*)d_out;

    void* args[] = { &p };
    hipLaunchCooperativeKernel((void*)fused_crossvit, dim3(256), dim3(256),
                               args, 0, stream);
}

// Round 5
// 162.035 us; speedup vs baseline: 1.8837x; 1.8837x over previous
//
#include <hip/hip_runtime.h>
#include <math.h>

#define NT   196
#define EMB  256
#define NH   8
#define DH   32
#define HID  1024
#define EPSV 1e-5f

// 4x4-register-blocked K-panel: 1 float4 W load + 1 broadcast b128 X read +
// 16 fma per iter. Threads: cq = t&63 (col quad), ks = t>>6 (K split of 4).
#define GEMM_PANEL(Wptr, ldw, xsT, pp, cq, ks, KITER)                          \
    {                                                                          \
        const float* Wb = (Wptr);                                              \
        float4 a0 = {0,0,0,0}, a1 = a0, a2 = a0, a3 = a0;                      \
        _Pragma("unroll 8")                                                    \
        for (int kk = (ks) * (KITER); kk < (ks) * (KITER) + (KITER); kk++) {   \
            float4 w4 = *(const float4*)&Wb[kk * (ldw)];                       \
            float4 xr = *(const float4*)&(xsT)[kk * 4];                        \
            a0.x = fmaf(xr.x, w4.x, a0.x); a0.y = fmaf(xr.x, w4.y, a0.y);      \
            a0.z = fmaf(xr.x, w4.z, a0.z); a0.w = fmaf(xr.x, w4.w, a0.w);      \
            a1.x = fmaf(xr.y, w4.x, a1.x); a1.y = fmaf(xr.y, w4.y, a1.y);      \
            a1.z = fmaf(xr.y, w4.z, a1.z); a1.w = fmaf(xr.y, w4.w, a1.w);      \
            a2.x = fmaf(xr.z, w4.x, a2.x); a2.y = fmaf(xr.z, w4.y, a2.y);      \
            a2.z = fmaf(xr.z, w4.z, a2.z); a2.w = fmaf(xr.z, w4.w, a2.w);      \
            a3.x = fmaf(xr.w, w4.x, a3.x); a3.y = fmaf(xr.w, w4.y, a3.y);      \
            a3.z = fmaf(xr.w, w4.z, a3.z); a3.w = fmaf(xr.w, w4.w, a3.w);      \
        }                                                                      \
        *(float4*)&(pp)[((ks) * 4 + 0) * 256 + (cq) * 4] = a0;                 \
        *(float4*)&(pp)[((ks) * 4 + 1) * 256 + (cq) * 4] = a1;                 \
        *(float4*)&(pp)[((ks) * 4 + 2) * 256 + (cq) * 4] = a2;                 \
        *(float4*)&(pp)[((ks) * 4 + 3) * 256 + (cq) * 4] = a3;                 \
    }

// ---------------- K1: QKV (raw input @ Wqkv + bias, de-interleave) ----------
// grid = 2 * 49 * 3 = 294 blocks (stream, token-tile of 4, col-group of 256)
__global__ __launch_bounds__(256) void k1_qkv(
    const float* __restrict__ vis, const float* __restrict__ ir,
    const float* __restrict__ Wqkv_v, const float* __restrict__ bqkv_v,
    const float* __restrict__ Wqkv_i, const float* __restrict__ bqkv_i,
    float* __restrict__ Q, float* __restrict__ Kq, float* __restrict__ Vq)
{
    const int b = blockIdx.x;
    const int s = b / 147;
    const int rem = b % 147;
    const int n0 = (rem / 3) * 4;
    const int cg = rem % 3;
    const int t = threadIdx.x;

    const float* x    = (s == 0) ? vis    : ir;
    const float* W    = (s == 0) ? Wqkv_v : Wqkv_i;
    const float* bias = (s == 0) ? bqkv_v : bqkv_i;

    __shared__ float xsT[EMB * 4];
    __shared__ float pp[4 * 4 * 256];

    {
        int r = t >> 6, c4 = (t & 63) * 4;
        float4 xv = *(const float4*)&x[(n0 + r) * EMB + c4];
        xsT[(c4 + 0) * 4 + r] = xv.x;
        xsT[(c4 + 1) * 4 + r] = xv.y;
        xsT[(c4 + 2) * 4 + r] = xv.z;
        xsT[(c4 + 3) * 4 + r] = xv.w;
    }
    __syncthreads();

    const int cq = t & 63, ks = t >> 6;
    GEMM_PANEL(W + cg * 256 + cq * 4, 768, xsT, pp, cq, ks, 64);
    __syncthreads();

    const int col = cg * 256 + t;
    const int h = col / 96, rr = col % 96, d = rr / 3, q = rr % 3;
    float* dst = (q == 0) ? Q : (q == 1 ? Kq : Vq);
    const float bval = bias[col];
    #pragma unroll
    for (int r = 0; r < 4; r++) {
        float v = pp[(0 * 4 + r) * 256 + t] + pp[(1 * 4 + r) * 256 + t]
                + pp[(2 * 4 + r) * 256 + t] + pp[(3 * 4 + r) * 256 + t] + bval;
        dst[((s * NH + h) * NT + n0 + r) * DH + d] = v;
    }
}

// ---------------- K2: cross-attention ----------------
// grid = 2*8*14 = 224 blocks (stream, head, 14-row tile). 256 threads = 4 waves.
__global__ __launch_bounds__(256) void k2_attn(
    const float* __restrict__ Q, const float* __restrict__ Kq,
    const float* __restrict__ Vq, float* __restrict__ AO)
{
    const int b  = blockIdx.x;
    const int s  = b / 112;
    const int rm = b % 112;
    const int h  = rm / 14;
    const int rt = rm % 14;
    const int t    = threadIdx.x;
    const int wv   = t >> 6;
    const int lane = t & 63;

    __shared__ float kl[NT * 33];
    __shared__ float vl[NT * 33];
    __shared__ float pb[4][NT];

    const float4* Ks4 = (const float4*)(Kq + ((1 - s) * NH + h) * NT * DH);
    const float4* Vs4 = (const float4*)(Vq + ((1 - s) * NH + h) * NT * DH);
    for (int idx = t; idx < NT * 8; idx += 256) {
        int j = idx >> 3, d4 = (idx & 7) * 4;
        float4 kv = Ks4[idx];
        kl[j * 33 + d4 + 0] = kv.x; kl[j * 33 + d4 + 1] = kv.y;
        kl[j * 33 + d4 + 2] = kv.z; kl[j * 33 + d4 + 3] = kv.w;
        float4 vv = Vs4[idx];
        vl[j * 33 + d4 + 0] = vv.x; vl[j * 33 + d4 + 1] = vv.y;
        vl[j * 33 + d4 + 2] = vv.z; vl[j * 33 + d4 + 3] = vv.w;
    }
    __syncthreads();

    const float* Qs = Q + ((s * NH + h) * NT) * DH;
    const bool v3 = (lane + 192) < NT;
    const int  j3 = v3 ? (lane + 192) : 0;

    for (int it = 0; it < 4; it++) {
        int lr = it * 4 + wv;
        bool act = lr < 14;
        int i = rt * 14 + lr;
        float inv_sum = 0.0f;
        if (act) {
            float qreg[DH];
            #pragma unroll
            for (int d = 0; d < DH; d++) qreg[d] = Qs[i * DH + d];
            float s0 = 0.f, s1 = 0.f, s2 = 0.f, s3 = 0.f;
            #pragma unroll
            for (int d = 0; d < DH; d++) {
                float qd = qreg[d];
                s0 = fmaf(qd, kl[(lane      ) * 33 + d], s0);
                s1 = fmaf(qd, kl[(lane +  64) * 33 + d], s1);
                s2 = fmaf(qd, kl[(lane + 128) * 33 + d], s2);
                s3 = fmaf(qd, kl[ j3          * 33 + d], s3);
            }
            const float sc = 1.0f / 16.0f;
            s0 *= sc; s1 *= sc; s2 *= sc; s3 *= sc;
            float m = fmaxf(fmaxf(s0, s1), v3 ? fmaxf(s2, s3) : s2);
            #pragma unroll
            for (int mk = 32; mk >= 1; mk >>= 1) m = fmaxf(m, __shfl_xor(m, mk));
            float p0 = expf(s0 - m), p1 = expf(s1 - m), p2 = expf(s2 - m);
            float p3 = v3 ? expf(s3 - m) : 0.0f;
            float ls = p0 + p1 + p2 + p3;
            #pragma unroll
            for (int mk = 32; mk >= 1; mk >>= 1) ls += __shfl_xor(ls, mk);
            inv_sum = 1.0f / ls;
            pb[wv][lane]       = p0;
            pb[wv][lane +  64] = p1;
            pb[wv][lane + 128] = p2;
            if (v3) pb[wv][lane + 192] = p3;
        }
        __syncthreads();
        if (act) {
            int d = lane & 31, half = lane >> 5;
            float o = 0.0f;
            int jb = half * 98;
            for (int jj = 0; jj < 98; jj++) {
                int j = jb + jj;
                o = fmaf(pb[wv][j], vl[j * 33 + d], o);
            }
            o += __shfl_xor(o, 32);
            if (lane < 32) AO[(s * NT + i) * EMB + h * DH + d] = o * inv_sum;
        }
        __syncthreads();
    }
}

// ---------------- K3 tail: proj + LN1-res + LN2 + FFN1 + GELU + FFN2 + recon
// grid = 2 * 49 = 98 blocks (4-token tiles). LV and HH never touch global.
__global__ __launch_bounds__(256) void k3_tail(
    const float* __restrict__ vis, const float* __restrict__ ir,
    const float* __restrict__ AO,
    const float* __restrict__ ln1v_w, const float* __restrict__ ln1v_b,
    const float* __restrict__ ln1i_w, const float* __restrict__ ln1i_b,
    const float* __restrict__ Wp_v, const float* __restrict__ bp_v,
    const float* __restrict__ Wp_i, const float* __restrict__ bp_i,
    const float* __restrict__ ln2v_w, const float* __restrict__ ln2v_b,
    const float* __restrict__ ln2i_w, const float* __restrict__ ln2i_b,
    const float* __restrict__ W1v, const float* __restrict__ b1v,
    const float* __restrict__ W1i, const float* __restrict__ b1i,
    const float* __restrict__ W2v, const float* __restrict__ b2v,
    const float* __restrict__ W2i, const float* __restrict__ b2i,
    float* __restrict__ out)
{
    const int b = blockIdx.x;
    const int s = b / 49;
    const int n0 = (b % 49) * 4;
    const int t = threadIdx.x;

    const float* x   = (s == 0) ? vis    : ir;
    const float* Wp  = (s == 0) ? Wp_v   : Wp_i;
    const float* bp  = (s == 0) ? bp_v   : bp_i;
    const float* l1w = (s == 0) ? ln1v_w : ln1i_w;
    const float* l1b = (s == 0) ? ln1v_b : ln1i_b;
    const float* l2w = (s == 0) ? ln2v_w : ln2i_w;
    const float* l2b = (s == 0) ? ln2v_b : ln2i_b;
    const float* W1  = (s == 0) ? W1v    : W1i;
    const float* bb1 = (s == 0) ? b1v    : b1i;
    const float* W2  = (s == 0) ? W2v    : W2i;
    const float* bb2 = (s == 0) ? b2v    : b2i;

    // 13312 floats = 52 KB
    __shared__ float smem[13312];
    float* aoT  = smem;            // [256][4]   4 KB
    float* nvb  = smem + 1024;     // [4][256]   4 KB
    float* rbuf = smem + 2048;     // [4][256]   4 KB
    float* lvb  = smem + 3072;     // [4][256]   4 KB (LN2 out, row-major)
    float* lvT  = smem + 4096;     // [256][4]   4 KB (LN2 out, transposed)
    float* hhT  = smem + 5120;     // [1024][4] 16 KB (GELU out, transposed)
    float* pp   = smem + 9216;     // [4][4][256] 16 KB

    const int r = t >> 6, lane = t & 63, c4 = lane * 4;
    const int cq = t & 63, ks = t >> 6;

    // ---- Phase A: LN1(x) + AO transpose (wave r = token r) ----
    {
        float4 xv = *(const float4*)&x[(n0 + r) * EMB + c4];
        float sum = xv.x + xv.y + xv.z + xv.w;
        float sq  = xv.x*xv.x + xv.y*xv.y + xv.z*xv.z + xv.w*xv.w;
        #pragma unroll
        for (int mk = 32; mk >= 1; mk >>= 1) {
            sum += __shfl_xor(sum, mk);
            sq  += __shfl_xor(sq,  mk);
        }
        float mean = sum * (1.0f / EMB);
        float inv  = rsqrtf(sq * (1.0f / EMB) - mean * mean + EPSV);
        float4 wv4 = *(const float4*)&l1w[c4];
        float4 bv4 = *(const float4*)&l1b[c4];
        nvb[r * 256 + c4 + 0] = (xv.x - mean) * inv * wv4.x + bv4.x;
        nvb[r * 256 + c4 + 1] = (xv.y - mean) * inv * wv4.y + bv4.y;
        nvb[r * 256 + c4 + 2] = (xv.z - mean) * inv * wv4.z + bv4.z;
        nvb[r * 256 + c4 + 3] = (xv.w - mean) * inv * wv4.w + bv4.w;
        float4 av = *(const float4*)&AO[(s * NT + n0 + r) * EMB + c4];
        aoT[(c4 + 0) * 4 + r] = av.x;
        aoT[(c4 + 1) * 4 + r] = av.y;
        aoT[(c4 + 2) * 4 + r] = av.z;
        aoT[(c4 + 3) * 4 + r] = av.w;
    }
    __syncthreads();

    // ---- Phase B: proj GEMM (4 tokens x 256 cols, K=256 split 4) ----
    GEMM_PANEL(Wp + cq * 4, EMB, aoT, pp, cq, ks, 64);
    __syncthreads();

    // ---- Phase C: residual + LN2 -> lvb (rows) + lvT (transposed) ----
    {
        const float bval = bp[t];
        #pragma unroll
        for (int r2 = 0; r2 < 4; r2++) {
            float v = pp[(0 * 4 + r2) * 256 + t] + pp[(1 * 4 + r2) * 256 + t]
                    + pp[(2 * 4 + r2) * 256 + t] + pp[(3 * 4 + r2) * 256 + t]
                    + bval + nvb[r2 * 256 + t];
            rbuf[r2 * 256 + t] = v;
        }
    }
    __syncthreads();
    {
        float4 rv = *(const float4*)&rbuf[r * 256 + c4];
        float sum = rv.x + rv.y + rv.z + rv.w;
        float sq  = rv.x*rv.x + rv.y*rv.y + rv.z*rv.z + rv.w*rv.w;
        #pragma unroll
        for (int mk = 32; mk >= 1; mk >>= 1) {
            sum += __shfl_xor(sum, mk);
            sq  += __shfl_xor(sq,  mk);
        }
        float mean = sum * (1.0f / EMB);
        float inv  = rsqrtf(sq * (1.0f / EMB) - mean * mean + EPSV);
        float4 wv4 = *(const float4*)&l2w[c4];
        float4 bv4 = *(const float4*)&l2b[c4];
        float4 o;
        o.x = (rv.x - mean) * inv * wv4.x + bv4.x;
        o.y = (rv.y - mean) * inv * wv4.y + bv4.y;
        o.z = (rv.z - mean) * inv * wv4.z + bv4.z;
        o.w = (rv.w - mean) * inv * wv4.w + bv4.w;
        *(float4*)&lvb[r * 256 + c4] = o;
        lvT[(c4 + 0) * 4 + r] = o.x;
        lvT[(c4 + 1) * 4 + r] = o.y;
        lvT[(c4 + 2) * 4 + r] = o.z;
        lvT[(c4 + 3) * 4 + r] = o.w;
    }
    __syncthreads();

    // ---- Phase D: FFN1 + GELU (4 tokens x 1024 cols; thread = 4 cols) ----
    {
        const int cD = t * 4;
        float4 a0 = {0,0,0,0}, a1 = a0, a2 = a0, a3 = a0;
        #pragma unroll 8
        for (int kk = 0; kk < EMB; kk++) {
            float4 w4 = *(const float4*)&W1[kk * HID + cD];
            float4 xr = *(const float4*)&lvT[kk * 4];
            a0.x = fmaf(xr.x, w4.x, a0.x); a0.y = fmaf(xr.x, w4.y, a0.y);
            a0.z = fmaf(xr.x, w4.z, a0.z); a0.w = fmaf(xr.x, w4.w, a0.w);
            a1.x = fmaf(xr.y, w4.x, a1.x); a1.y = fmaf(xr.y, w4.y, a1.y);
            a1.z = fmaf(xr.y, w4.z, a1.z); a1.w = fmaf(xr.y, w4.w, a1.w);
            a2.x = fmaf(xr.z, w4.x, a2.x); a2.y = fmaf(xr.z, w4.y, a2.y);
            a2.z = fmaf(xr.z, w4.z, a2.z); a2.w = fmaf(xr.z, w4.w, a2.w);
            a3.x = fmaf(xr.w, w4.x, a3.x); a3.y = fmaf(xr.w, w4.y, a3.y);
            a3.z = fmaf(xr.w, w4.z, a3.z); a3.w = fmaf(xr.w, w4.w, a3.w);
        }
        float4 bv4 = *(const float4*)&bb1[cD];
        a0.x += bv4.x; a0.y += bv4.y; a0.z += bv4.z; a0.w += bv4.w;
        a1.x += bv4.x; a1.y += bv4.y; a1.z += bv4.z; a1.w += bv4.w;
        a2.x += bv4.x; a2.y += bv4.y; a2.z += bv4.z; a2.w += bv4.w;
        a3.x += bv4.x; a3.y += bv4.y; a3.z += bv4.z; a3.w += bv4.w;
        const float k = 0.7071067811865475f;
        #define GELU(v) (0.5f * (v) * (1.0f + erff((v) * k)))
        // store transposed: hhT[col*4 + r], b128 per col
        float4 h0 = { GELU(a0.x), GELU(a1.x), GELU(a2.x), GELU(a3.x) };
        float4 h1 = { GELU(a0.y), GELU(a1.y), GELU(a2.y), GELU(a3.y) };
        float4 h2 = { GELU(a0.z), GELU(a1.z), GELU(a2.z), GELU(a3.z) };
        float4 h3 = { GELU(a0.w), GELU(a1.w), GELU(a2.w), GELU(a3.w) };
        #undef GELU
        *(float4*)&hhT[(cD + 0) * 4] = h0;
        *(float4*)&hhT[(cD + 1) * 4] = h1;
        *(float4*)&hhT[(cD + 2) * 4] = h2;
        *(float4*)&hhT[(cD + 3) * 4] = h3;
    }
    __syncthreads();

    // ---- Phase E: FFN2 (K=1024 split 4) + bias + residual + recon ----
    GEMM_PANEL(W2 + cq * 4, EMB, hhT, pp, cq, ks, 256);
    __syncthreads();
    {
        const float bval = bb2[t];
        const int p1 = t >> 4, p2 = t & 15;
        const int ch = (s == 0) ? 1 : 0;   // channel 0 = ir, 1 = vis
        #pragma unroll
        for (int r2 = 0; r2 < 4; r2++) {
            int n = n0 + r2;
            float v = pp[(0 * 4 + r2) * 256 + t] + pp[(1 * 4 + r2) * 256 + t]
                    + pp[(2 * 4 + r2) * 256 + t] + pp[(3 * 4 + r2) * 256 + t]
                    + bval + lvb[r2 * 256 + t];
            int n1 = n / 14, n2 = n % 14;
            int f = p1 * 3136 + p2 * 196 + n1 * 14 + n2;
            out[ch * 50176 + f] = v;
        }
    }
}

extern "C" void kernel_launch(void* const* d_in, const int* in_sizes, int n_in,
                              void* d_out, int out_size, void* d_ws, size_t ws_size,
                              hipStream_t stream)
{
    const float* vis    = (const float*)d_in[0];
    const float* ir     = (const float*)d_in[1];
    const float* ln1v_w = (const float*)d_in[2];
    const float* ln1v_b = (const float*)d_in[3];
    const float* ln1i_w = (const float*)d_in[4];
    const float* ln1i_b = (const float*)d_in[5];
    const float* ln2v_w = (const float*)d_in[6];
    const float* ln2v_b = (const float*)d_in[7];
    const float* ln2i_w = (const float*)d_in[8];
    const float* ln2i_b = (const float*)d_in[9];
    const float* Wqkv_v = (const float*)d_in[10];
    const float* bqkv_v = (const float*)d_in[11];
    const float* Wqkv_i = (const float*)d_in[12];
    const float* bqkv_i = (const float*)d_in[13];
    const float* Wp_v   = (const float*)d_in[14];
    const float* bp_v   = (const float*)d_in[15];
    const float* Wp_i   = (const float*)d_in[16];
    const float* bp_i   = (const float*)d_in[17];
    const float* W1v    = (const float*)d_in[18];
    const float* b1v    = (const float*)d_in[19];
    const float* W2v    = (const float*)d_in[20];
    const float* b2v    = (const float*)d_in[21];
    const float* W1i    = (const float*)d_in[22];
    const float* b1i    = (const float*)d_in[23];
    const float* W2i    = (const float*)d_in[24];
    const float* b2i    = (const float*)d_in[25];

    float* ws = (float*)d_ws;
    float* Q  = ws;               // [2][8][196][32]
    float* K  = ws + 100352;
    float* V  = ws + 200704;
    float* AO = ws + 301056;      // [2][196][256]

    k1_qkv<<<294, 256, 0, stream>>>(vis, ir, Wqkv_v, bqkv_v, Wqkv_i, bqkv_i, Q, K, V);
    k2_attn<<<224, 256, 0, stream>>>(Q, K, V, AO);
    k3_tail<<<98, 256, 0, stream>>>(vis, ir, AO,
                                    ln1v_w, ln1v_b, ln1i_w, ln1i_b,
                                    Wp_v, bp_v, Wp_i, bp_i,
                                    ln2v_w, ln2v_b, ln2i_w, ln2i_b,
                                    W1v, b1v, W1i, b1i,
                                    W2v, b2v, W2i, b2i,
                                    (float*)d_out);
}